// Round 3
// baseline (1658.964 us; speedup 1.0000x reference)
//
#include <hip/hip_runtime.h>

// VariationalGCNEncoder: 2-layer GCN (512 -> 4 -> [2,2]), N=100k nodes, E=3.2M edges.
//
// R9: delete ALL edge preprocessing (bucket sort, CSR build). Aggregation is done
// with direct memory-side fp32 atomics (unsafeAtomicAdd -> global_atomic_add_f32):
// each edge does one random 16B read (L2-resident source array) and 4 atomic adds
// into SoA accumulators (4 x 400KB, LLC-resident; SoA spreads one edge's 4 atomics
// across different cache slices). Scattered atomics are 4B memory-side RMWs - no
// write-allocate line thrash (the thing the old bucket sort was built to avoid).
//
//   k_zero  : zero deg + agg1 + agg2 accumulators (one contiguous region)
//   k_deg   : deg[dst]++ over edges (int atomics)
//   k_lin1  : hls = (x @ W1) * rsqrt(deg+1); also stores dinv  (wave-per-row)
//   k_s1    : edge scatter: agg1[c][dst] += hls[src].c   (4 fp32 atomics/edge)
//   k_post1 : h = relu((agg1+hls[n])*dinv + b1); ts[n] = (h@[Wmu|Wls])*dinv
//   k_s2    : edge scatter: agg2[c][dst] += ts[src].c
//   k_post2 : mu/logstd = (agg2+ts[n])*dinv + b  -> d_out

constexpr int N_NODES = 100000;
constexpr int N_EDGES = 3200000;
constexpr int IN_CH   = 512;

// zero region: deg (N ints) + agg1 (4N floats) + agg2 (4N floats) = 9N words
constexpr int ZERO_WORDS = 9 * N_NODES;

__global__ __launch_bounds__(256) void k_zero(float* __restrict__ buf) {
    int i = blockIdx.x * blockDim.x + threadIdx.x;
    int n4 = ZERO_WORDS / 4;                       // 225000 float4s
    if (i < n4) ((float4*)buf)[i] = make_float4(0.f, 0.f, 0.f, 0.f);
}

__global__ __launch_bounds__(256) void k_deg(const int* __restrict__ dst,
                                             int* __restrict__ deg) {
    int e = blockIdx.x * blockDim.x + threadIdx.x;
    if (e < N_EDGES) {
        int d = dst[e];
        if ((unsigned)d < (unsigned)N_NODES) atomicAdd(&deg[d], 1);
    }
}

// hls[row] = (x[row,:] @ W1) * dinv[row]; dinv[row] = rsqrt(deg+1). Wave per row.
__global__ __launch_bounds__(256) void k_lin1(const float* __restrict__ x,
                                              const float* __restrict__ W1,
                                              const int* __restrict__ deg,
                                              float* __restrict__ dinv,
                                              float* __restrict__ h) {
    int wave = threadIdx.x >> 6, lane = threadIdx.x & 63;
    int row = blockIdx.x * 4 + wave;
    if (row >= N_NODES) return;
    const float4* x4 = (const float4*)(x + (size_t)row * IN_CH);
    const float4* w4 = (const float4*)W1;
    float4 acc = make_float4(0.f, 0.f, 0.f, 0.f);
#pragma unroll
    for (int j = 0; j < 2; ++j) {
        int idx = lane + 64 * j;
        float4 v = x4[idx];
        int kb = 4 * idx;
        float4 wa = w4[kb + 0], wb = w4[kb + 1], wc = w4[kb + 2], wd = w4[kb + 3];
        acc.x += v.x * wa.x + v.y * wb.x + v.z * wc.x + v.w * wd.x;
        acc.y += v.x * wa.y + v.y * wb.y + v.z * wc.y + v.w * wd.y;
        acc.z += v.x * wa.z + v.y * wb.z + v.z * wc.z + v.w * wd.z;
        acc.w += v.x * wa.w + v.y * wb.w + v.z * wc.w + v.w * wd.w;
    }
#pragma unroll
    for (int off = 32; off > 0; off >>= 1) {
        acc.x += __shfl_down(acc.x, off);
        acc.y += __shfl_down(acc.y, off);
        acc.z += __shfl_down(acc.z, off);
        acc.w += __shfl_down(acc.w, off);
    }
    if (lane == 0) {
        float di = rsqrtf((float)(deg[row] + 1));   // +1 self loop
        dinv[row] = di;
        ((float4*)h)[row] = make_float4(acc.x * di, acc.y * di, acc.z * di, acc.w * di);
    }
}

// Edge scatter: agg[c][dst] += g[src].c  (SoA accumulators, one edge per thread).
__global__ __launch_bounds__(256) void k_scat(const int* __restrict__ src,
                                              const int* __restrict__ dst,
                                              const float* __restrict__ g,
                                              float* __restrict__ agg) {
    int e = blockIdx.x * blockDim.x + threadIdx.x;
    if (e >= N_EDGES) return;
    int s = src[e], d = dst[e];
    if ((unsigned)s >= (unsigned)N_NODES || (unsigned)d >= (unsigned)N_NODES) return;
    float4 v = ((const float4*)g)[s];
    unsafeAtomicAdd(&agg[0 * N_NODES + d], v.x);
    unsafeAtomicAdd(&agg[1 * N_NODES + d], v.y);
    unsafeAtomicAdd(&agg[2 * N_NODES + d], v.z);
    unsafeAtomicAdd(&agg[3 * N_NODES + d], v.w);
}

// Node epilogue 1: h = relu((agg1 + hls[n])*dinv + b1); ts = (h@[Wmu|Wls])*dinv.
__global__ __launch_bounds__(256) void k_post1(const float* __restrict__ agg1,
                                               const float* __restrict__ hls,
                                               const float* __restrict__ dinv,
                                               const float* __restrict__ b1,
                                               const float* __restrict__ Wmu,
                                               const float* __restrict__ Wls,
                                               float* __restrict__ ts) {
    int n = blockIdx.x * blockDim.x + threadIdx.x;
    if (n >= N_NODES) return;
    float di = dinv[n];
    float4 self = ((const float4*)hls)[n];
    float h0 = fmaxf((agg1[0 * N_NODES + n] + self.x) * di + b1[0], 0.f);
    float h1 = fmaxf((agg1[1 * N_NODES + n] + self.y) * di + b1[1], 0.f);
    float h2 = fmaxf((agg1[2 * N_NODES + n] + self.z) * di + b1[2], 0.f);
    float h3 = fmaxf((agg1[3 * N_NODES + n] + self.w) * di + b1[3], 0.f);
    float4 o;
    o.x = (h0 * Wmu[0] + h1 * Wmu[2] + h2 * Wmu[4] + h3 * Wmu[6]) * di;
    o.y = (h0 * Wmu[1] + h1 * Wmu[3] + h2 * Wmu[5] + h3 * Wmu[7]) * di;
    o.z = (h0 * Wls[0] + h1 * Wls[2] + h2 * Wls[4] + h3 * Wls[6]) * di;
    o.w = (h0 * Wls[1] + h1 * Wls[3] + h2 * Wls[5] + h3 * Wls[7]) * di;
    ((float4*)ts)[n] = o;
}

// Node epilogue 2: mu/logstd = (agg2 + ts[n])*dinv + b  -> out.
__global__ __launch_bounds__(256) void k_post2(const float* __restrict__ agg2,
                                               const float* __restrict__ ts,
                                               const float* __restrict__ dinv,
                                               const float* __restrict__ bmu,
                                               const float* __restrict__ bls,
                                               float* __restrict__ out) {
    int n = blockIdx.x * blockDim.x + threadIdx.x;
    if (n >= N_NODES) return;
    float di = dinv[n];
    float4 self = ((const float4*)ts)[n];
    float2 mu = make_float2((agg2[0 * N_NODES + n] + self.x) * di + bmu[0],
                            (agg2[1 * N_NODES + n] + self.y) * di + bmu[1]);
    float2 ls = make_float2((agg2[2 * N_NODES + n] + self.z) * di + bls[0],
                            (agg2[3 * N_NODES + n] + self.w) * di + bls[1]);
    ((float2*)out)[n] = mu;
    ((float2*)(out + 2 * N_NODES))[n] = ls;
}

extern "C" void kernel_launch(void* const* d_in, const int* in_sizes, int n_in,
                              void* d_out, int out_size, void* d_ws, size_t ws_size,
                              hipStream_t stream) {
    const float* x    = (const float*)d_in[0];
    const int*   ei   = (const int*)d_in[1];    // [2, E] int32: src row then dst row
    const float* W1   = (const float*)d_in[2];
    const float* b1   = (const float*)d_in[3];
    const float* Wmu  = (const float*)d_in[4];
    const float* bmu  = (const float*)d_in[5];
    const float* Wls  = (const float*)d_in[6];
    const float* bls  = (const float*)d_in[7];
    float* out = (float*)d_out;

    const int* src = ei;
    const int* dst = ei + N_EDGES;

    // workspace layout (~6.1 MB). [deg|agg1|agg2] contiguous for one-shot zeroing.
    char* p = (char*)d_ws;
    int*   deg   = (int*)p;     p += (size_t)N_NODES * 4;        // N ints
    float* agg1  = (float*)p;   p += (size_t)N_NODES * 16;       // SoA [4][N]
    float* agg2  = (float*)p;   p += (size_t)N_NODES * 16;       // SoA [4][N]
    float* dinv  = (float*)p;   p += (size_t)N_NODES * 4;
    float* hls   = (float*)p;   p += (size_t)N_NODES * 16;
    float* ts    = (float*)p;   p += (size_t)N_NODES * 16;

    const int TB = 256;
    int gZ = (ZERO_WORDS / 4 + TB - 1) / TB;   // 879
    int gE = (N_EDGES + TB - 1) / TB;          // 12500
    int gL = (N_NODES + 3) / 4;                // 25000
    int gN = (N_NODES + TB - 1) / TB;          // 391

    k_zero <<<gZ, TB, 0, stream>>>((float*)deg);
    k_deg  <<<gE, TB, 0, stream>>>(dst, deg);
    k_lin1 <<<gL, TB, 0, stream>>>(x, W1, deg, dinv, hls);
    k_scat <<<gE, TB, 0, stream>>>(src, dst, hls, agg1);
    k_post1<<<gN, TB, 0, stream>>>(agg1, hls, dinv, b1, Wmu, Wls, ts);
    k_scat <<<gE, TB, 0, stream>>>(src, dst, ts, agg2);
    k_post2<<<gN, TB, 0, stream>>>(agg2, ts, dinv, bmu, bls, out);
}

// Round 4
// 382.333 us; speedup vs baseline: 4.3391x; 4.3391x over previous
//
#include <hip/hip_runtime.h>

// VariationalGCNEncoder: 2-layer GCN (512 -> 4 -> [2,2]), N=100k nodes, E=3.2M edges.
//
// R10: revert to the proven R6 structure (bucket sort -> per-node sort -> CSR ->
// 8-thread/node register-gather aggregation; 396us), plus two mechanical wins:
//  (1) fuse part1 + lin1 into one kernel (part1 blocks first, then lin1 blocks):
//      part1 is LDS/latency-bound with ~0 HBM use; lin1 is HBM-bound (204.8MB x
//      read). They are independent once lin1's dinv scaling is deferred to
//      part2's tail (hls rescaled in place there). Overlap ~= max instead of sum.
//  (2) part2 stages ebuf1 into LDS once (stag[CAP]) instead of two global passes.
// R7-R9 lessons: LDS fp32 atomic agg and global fp32 atomic scatter are both
// far slower than the register-gather CSR design (R9: 48ns/atomic, write-through).
//
//   k_zero  : bcur[b] = b*CAP
//   k_fused : blocks [0,241): tile->LDS 2-pass bucket sort (782 buckets of 128),
//             coalesced writeout to ebuf1 (packed (s<<7)|(d&127));
//             blocks [241,12741): hls_raw = x @ W1 (wave-per-row, float4)
//   k_part2 : per-bucket node sort in LDS (single ebuf1 read), linear writeout
//             to ebuf2; emits nstart/ncnt/dinv; rescales hls *= dinv in place
//   k_agg1  : per-node CSR gather (8 thr/node, reg acc) -> relu -> ts=(h@[Wmu|Wls])*dinv
//   k_agg2  : same on ts -> mu, logstd -> d_out

constexpr int N_NODES = 100000;
constexpr int N_EDGES = 3200000;
constexpr int IN_CH   = 512;
constexpr int BK_SH   = 7;                       // 128 nodes per bucket
constexpr int BK_N    = 1 << BK_SH;              // 128
constexpr int KC      = (N_NODES + BK_N - 1) / BK_N;    // 782
constexpr int CAP     = 4608;                    // per-bucket capacity (mean 4092)
constexpr int T_TILE  = 13312;                   // edges per part1 tile (52 KB LDS)
constexpr int NT_P1   = (N_EDGES + T_TILE - 1) / T_TILE;  // 241
constexpr int ROWS_PB = 8;                       // lin1 rows per 512-thread block
constexpr int NB_LIN  = (N_NODES + ROWS_PB - 1) / ROWS_PB;  // 12500

__global__ __launch_bounds__(256) void k_zero(int* __restrict__ bcur) {
    int i = blockIdx.x * blockDim.x + threadIdx.x;
    if (i < KC) bcur[i] = i * CAP;
}

// Fused: part1 bucket sort (blocks < NT_P1) + lin1 raw GEMV (remaining blocks).
__global__ __launch_bounds__(512) void k_fused(const int* __restrict__ src,
                                               const int* __restrict__ dst,
                                               int* __restrict__ bcur,
                                               int* __restrict__ ebuf1,
                                               const float* __restrict__ x,
                                               const float* __restrict__ W1,
                                               float* __restrict__ h) {
    __shared__ int sorted[T_TILE];   // 52 KB: bucket-sorted packed edges of this tile
    __shared__ int tstart[KC];       // tile-local exclusive bucket starts
    __shared__ int cur[KC];          // pass A: histogram; pass B: ranking cursor
    __shared__ int gbase[KC];        // reserved global base per bucket

    if (blockIdx.x < NT_P1) {
        // ---------------- part1: tile-wise bucket sort ----------------
        int tid = threadIdx.x;
        int e0 = blockIdx.x * T_TILE;
        int tcnt = min(T_TILE, N_EDGES - e0);

        for (int i = tid; i < KC; i += 512) cur[i] = 0;
        __syncthreads();

        // pass A: histogram dst buckets
        for (int j = tid; j < tcnt; j += 512) {
            int d = dst[e0 + j];
            if ((unsigned)d < (unsigned)N_NODES) atomicAdd(&cur[d >> BK_SH], 1);
        }
        __syncthreads();

        // scan cur -> tstart (782 entries, 2 per thread; temp in sorted[0..511])
        {
            int i0 = 2 * tid, i1 = 2 * tid + 1;
            int a0 = (i0 < KC) ? cur[i0] : 0;
            int a1 = (i1 < KC) ? cur[i1] : 0;
            int s = a0 + a1;
            sorted[tid] = s;
            __syncthreads();
            for (int off = 1; off < 512; off <<= 1) {
                int t = (tid >= off) ? sorted[tid - off] : 0;
                __syncthreads();
                sorted[tid] += t;
                __syncthreads();
            }
            int excl = sorted[tid] - s;
            if (i0 < KC) tstart[i0] = excl;
            if (i1 < KC) tstart[i1] = excl + a0;
            __syncthreads();
        }

        // reserve global space per bucket; convert cur -> ranking cursor
        for (int i = tid; i < KC; i += 512) {
            int c = cur[i];
            gbase[i] = c ? atomicAdd(&bcur[i], c) : 0;
            cur[i] = tstart[i];
        }
        __syncthreads();

        // pass B: rank + scatter into LDS (packed (s<<7)|(d&127); s < 2^17)
        for (int j = tid; j < tcnt; j += 512) {
            int s = src[e0 + j], d = dst[e0 + j];
            if ((unsigned)s < (unsigned)N_NODES && (unsigned)d < (unsigned)N_NODES) {
                int b = d >> BK_SH;
                int r = atomicAdd(&cur[b], 1);
                sorted[r] = (s << BK_SH) | (d & (BK_N - 1));
            }
        }
        __syncthreads();

        // writeout: wave-per-bucket, contiguous LDS run -> contiguous global segment
        int wv = tid >> 6, ln = tid & 63;
        for (int b = wv; b < KC; b += 8) {
            int st = tstart[b];
            int c  = cur[b] - st;               // bucket count in this tile
            int gb = gbase[b];
            int avail = (b + 1) * CAP - gb;     // capacity guard (unreachable statistically)
            if (avail < c) c = max(avail, 0);
            for (int j = ln; j < c; j += 64)
                ebuf1[gb + j] = sorted[st + j];
        }
    } else {
        // ---------------- lin1: hls_raw[row] = x[row,:] @ W1 (no dinv yet) -------
        int wave = threadIdx.x >> 6, lane = threadIdx.x & 63;
        int row = (blockIdx.x - NT_P1) * ROWS_PB + wave;
        if (row >= N_NODES) return;
        const float4* x4 = (const float4*)(x + (size_t)row * IN_CH);
        const float4* w4 = (const float4*)W1;
        float4 acc = make_float4(0.f, 0.f, 0.f, 0.f);
#pragma unroll
        for (int j = 0; j < 2; ++j) {
            int idx = lane + 64 * j;
            float4 v = x4[idx];
            int kb = 4 * idx;
            float4 wa = w4[kb + 0], wb = w4[kb + 1], wc = w4[kb + 2], wd = w4[kb + 3];
            acc.x += v.x * wa.x + v.y * wb.x + v.z * wc.x + v.w * wd.x;
            acc.y += v.x * wa.y + v.y * wb.y + v.z * wc.y + v.w * wd.y;
            acc.z += v.x * wa.z + v.y * wb.z + v.z * wc.z + v.w * wd.z;
            acc.w += v.x * wa.w + v.y * wb.w + v.z * wc.w + v.w * wd.w;
        }
#pragma unroll
        for (int off = 32; off > 0; off >>= 1) {
            acc.x += __shfl_down(acc.x, off);
            acc.y += __shfl_down(acc.y, off);
            acc.z += __shfl_down(acc.z, off);
            acc.w += __shfl_down(acc.w, off);
        }
        if (lane == 0)
            ((float4*)h)[row] = acc;
    }
}

// Per-bucket node sort: single global read (LDS staging), linear coalesced
// writeout; CSR + dinv; rescale hls in place (deferred lin1 scaling).
__global__ __launch_bounds__(512) void k_part2(const int* __restrict__ bcur,
                                               const int* __restrict__ ebuf1,
                                               int* __restrict__ ebuf2,
                                               int* __restrict__ nstart,
                                               int* __restrict__ ncnt,
                                               float* __restrict__ dinv,
                                               float* __restrict__ hls) {
    __shared__ int stag[CAP];        // 18 KB: staged raw edges (single global read)
    __shared__ int sorted[CAP];      // 18 KB
    __shared__ int hist[BK_N], excl[BK_N], curx[BK_N];
    int b = blockIdx.x, tid = threadIdx.x;
    int base = b * CAP;
    int cnt = min(bcur[b] - base, CAP);

    if (tid < BK_N) hist[tid] = 0;
    __syncthreads();
    // pass A: stage + node histogram
    for (int j = tid; j < cnt; j += 512) {
        int e = ebuf1[base + j];
        stag[j] = e;
        atomicAdd(&hist[e & (BK_N - 1)], 1);
    }
    __syncthreads();
    // scan 128 entries (threads < 128 active, all threads hit barriers)
    if (tid < BK_N) excl[tid] = hist[tid];
    __syncthreads();
    for (int off = 1; off < BK_N; off <<= 1) {
        int t = (tid < BK_N && tid >= off) ? excl[tid - off] : 0;
        __syncthreads();
        if (tid < BK_N) excl[tid] += t;
        __syncthreads();
    }
    if (tid < BK_N) {
        int v = hist[tid];
        int ex = excl[tid] - v;             // exclusive
        excl[tid] = ex;
        curx[tid] = ex;
        int node = b * BK_N + tid;
        if (node < N_NODES) {
            nstart[node] = base + ex;
            ncnt[node]   = v;
            float di = rsqrtf((float)(v + 1));   // +1 self loop
            dinv[node]   = di;
            float4* h4 = (float4*)hls;           // deferred lin1 scaling
            float4 hv = h4[node];
            h4[node] = make_float4(hv.x * di, hv.y * di, hv.z * di, hv.w * di);
        }
    }
    __syncthreads();
    // pass B: rank + scatter into LDS (store src only; dst implied by position)
    for (int j = tid; j < cnt; j += 512) {
        int e = stag[j];
        int r = atomicAdd(&curx[e & (BK_N - 1)], 1);
        sorted[r] = e >> BK_SH;
    }
    __syncthreads();
    // linear coalesced writeout
    for (int j = tid; j < cnt; j += 512)
        ebuf2[base + j] = sorted[j];
}

// Gather-accumulate for one node: 8 threads/node, 2x unrolled, dual accumulators.
__device__ __forceinline__ float4 gather8(const int* __restrict__ ebuf2,
                                          const float4* __restrict__ g4,
                                          int st, int c, int r) {
    float4 a0 = make_float4(0.f, 0.f, 0.f, 0.f);
    float4 a1 = make_float4(0.f, 0.f, 0.f, 0.f);
    int j = st + r, last = st + c;
    for (; j + 8 < last; j += 16) {
        int i0 = ebuf2[j];
        int i1 = ebuf2[j + 8];
        float4 f0 = g4[i0];
        float4 f1 = g4[i1];
        a0.x += f0.x; a0.y += f0.y; a0.z += f0.z; a0.w += f0.w;
        a1.x += f1.x; a1.y += f1.y; a1.z += f1.z; a1.w += f1.w;
    }
    if (j < last) {
        float4 f = g4[ebuf2[j]];
        a0.x += f.x; a0.y += f.y; a0.z += f.z; a0.w += f.w;
    }
    a0.x += a1.x; a0.y += a1.y; a0.z += a1.z; a0.w += a1.w;
    a0.x += __shfl_xor(a0.x, 1); a0.y += __shfl_xor(a0.y, 1);
    a0.z += __shfl_xor(a0.z, 1); a0.w += __shfl_xor(a0.w, 1);
    a0.x += __shfl_xor(a0.x, 2); a0.y += __shfl_xor(a0.y, 2);
    a0.z += __shfl_xor(a0.z, 2); a0.w += __shfl_xor(a0.w, 2);
    a0.x += __shfl_xor(a0.x, 4); a0.y += __shfl_xor(a0.y, 4);
    a0.z += __shfl_xor(a0.z, 4); a0.w += __shfl_xor(a0.w, 4);
    return a0;
}

// Layer-1: agg = dinv_d*(sum hls[s] + hls[d]); h=relu(agg+b1); ts=(h@[Wmu|Wls])*dinv_d
__global__ __launch_bounds__(256) void k_agg1(const int* __restrict__ ebuf2,
                                              const int* __restrict__ nstart,
                                              const int* __restrict__ ncnt,
                                              const float* __restrict__ dinv,
                                              const float* __restrict__ hls,
                                              const float* __restrict__ b1,
                                              const float* __restrict__ Wmu,
                                              const float* __restrict__ Wls,
                                              float* __restrict__ ts) {
    int tid = threadIdx.x;
    int node = blockIdx.x * 32 + (tid >> 3);
    int r = tid & 7;
    if (node >= N_NODES) return;                 // octet-uniform exit
    const float4* g4 = (const float4*)hls;
    float4 a = gather8(ebuf2, g4, nstart[node], ncnt[node], r);
    if (r == 0) {
        float4 self = g4[node];
        float di = dinv[node];
        float h0 = fmaxf((a.x + self.x) * di + b1[0], 0.f);
        float h1 = fmaxf((a.y + self.y) * di + b1[1], 0.f);
        float h2 = fmaxf((a.z + self.z) * di + b1[2], 0.f);
        float h3 = fmaxf((a.w + self.w) * di + b1[3], 0.f);
        float4 o;
        o.x = (h0 * Wmu[0] + h1 * Wmu[2] + h2 * Wmu[4] + h3 * Wmu[6]) * di;
        o.y = (h0 * Wmu[1] + h1 * Wmu[3] + h2 * Wmu[5] + h3 * Wmu[7]) * di;
        o.z = (h0 * Wls[0] + h1 * Wls[2] + h2 * Wls[4] + h3 * Wls[6]) * di;
        o.w = (h0 * Wls[1] + h1 * Wls[3] + h2 * Wls[5] + h3 * Wls[7]) * di;
        ((float4*)ts)[node] = o;
    }
}

// Layer-2 aggregation on ts -> mu (out[0..2N)), logstd (out[2N..4N)).
__global__ __launch_bounds__(256) void k_agg2(const int* __restrict__ ebuf2,
                                              const int* __restrict__ nstart,
                                              const int* __restrict__ ncnt,
                                              const float* __restrict__ dinv,
                                              const float* __restrict__ ts,
                                              const float* __restrict__ bmu,
                                              const float* __restrict__ bls,
                                              float* __restrict__ out) {
    int tid = threadIdx.x;
    int node = blockIdx.x * 32 + (tid >> 3);
    int r = tid & 7;
    if (node >= N_NODES) return;
    const float4* g4 = (const float4*)ts;
    float4 a = gather8(ebuf2, g4, nstart[node], ncnt[node], r);
    if (r == 0) {
        float4 self = g4[node];
        float di = dinv[node];
        float2 mu = make_float2((a.x + self.x) * di + bmu[0],
                                (a.y + self.y) * di + bmu[1]);
        float2 ls = make_float2((a.z + self.z) * di + bls[0],
                                (a.w + self.w) * di + bls[1]);
        ((float2*)out)[node] = mu;
        ((float2*)(out + 2 * N_NODES))[node] = ls;
    }
}

extern "C" void kernel_launch(void* const* d_in, const int* in_sizes, int n_in,
                              void* d_out, int out_size, void* d_ws, size_t ws_size,
                              hipStream_t stream) {
    const float* x    = (const float*)d_in[0];
    const int*   ei   = (const int*)d_in[1];    // [2, E] int32: src row then dst row
    const float* W1   = (const float*)d_in[2];
    const float* b1   = (const float*)d_in[3];
    const float* Wmu  = (const float*)d_in[4];
    const float* bmu  = (const float*)d_in[5];
    const float* Wls  = (const float*)d_in[6];
    const float* bls  = (const float*)d_in[7];
    float* out = (float*)d_out;

    const int* src = ei;
    const int* dst = ei + N_EDGES;

    // workspace layout (~34 MB)
    char* p = (char*)d_ws;
    float* dinv   = (float*)p;  p += (size_t)N_NODES * 4;
    float* hls    = (float*)p;  p += (size_t)N_NODES * 16;
    float* ts     = (float*)p;  p += (size_t)N_NODES * 16;
    int*   nstart = (int*)p;    p += (size_t)N_NODES * 4;
    int*   ncnt   = (int*)p;    p += (size_t)N_NODES * 4;
    int*   bcur   = (int*)p;    p += (size_t)KC * 4;
    int*   ebuf1  = (int*)p;    p += (size_t)KC * CAP * 4;   // 14.4 MB
    int*   ebuf2  = (int*)p;    p += (size_t)KC * CAP * 4;   // 14.4 MB

    const int TB = 256;
    int gA = (N_NODES + 31) / 32;     // 3125

    k_zero <<<(KC + TB - 1) / TB, TB, 0, stream>>>(bcur);
    k_fused<<<NT_P1 + NB_LIN, 512, 0, stream>>>(src, dst, bcur, ebuf1, x, W1, hls);
    k_part2<<<KC,    512, 0, stream>>>(bcur, ebuf1, ebuf2, nstart, ncnt, dinv, hls);
    k_agg1 <<<gA,    TB,  0, stream>>>(ebuf2, nstart, ncnt, dinv, hls, b1, Wmu, Wls, ts);
    k_agg2 <<<gA,    TB,  0, stream>>>(ebuf2, nstart, ncnt, dinv, ts, bmu, bls, out);
}

// Round 5
// 382.007 us; speedup vs baseline: 4.3428x; 1.0009x over previous
//
#include <hip/hip_runtime.h>

// VariationalGCNEncoder: 2-layer GCN (512 -> 4 -> [2,2]), N=100k nodes, E=3.2M edges.
//
// R11 = R10 + agg1 fused into part2 (the sorted edge list is consumed in LDS,
// not round-tripped through ebuf2 for layer 1). Enabler: CSR/dinv/hls-rescale
// hoisted into k_csr (runs before part2), so hls[src] is globally scaled when
// the fused gather reads it. dinv array eliminated (recomputed as rsqrt(ncnt+1)).
// R7-R9 lessons: LDS fp32 atomic agg and global fp32 atomic scatter both lose
// badly to the sort + register-gather design (R9: ~48ns/global atomic).
//
//   k_zero   : bcur[b] = b*CAP
//   k_fused  : blocks [0,241): tile->LDS 2-pass bucket sort (782 buckets of 128),
//              coalesced writeout to ebuf1 (packed (s<<7)|(d&127));
//              blocks [241,12741): hls_raw = x @ W1 (wave-per-row, float4)
//   k_csr    : per-bucket node histogram of ebuf1 -> nstart/ncnt; hls *= dinv
//   k_p2agg1 : per-bucket: stage ebuf1 -> rank-sort in LDS -> write ebuf2;
//              then layer-1 gather IN LDS (4 thr/node) -> relu -> ts
//   k_agg2   : per-node CSR gather on ts (8 thr/node) -> mu, logstd -> d_out

constexpr int N_NODES = 100000;
constexpr int N_EDGES = 3200000;
constexpr int IN_CH   = 512;
constexpr int BK_SH   = 7;                       // 128 nodes per bucket
constexpr int BK_N    = 1 << BK_SH;              // 128
constexpr int KC      = (N_NODES + BK_N - 1) / BK_N;    // 782
constexpr int CAP     = 4608;                    // per-bucket capacity (mean 4092)
constexpr int T_TILE  = 13312;                   // edges per part1 tile (52 KB LDS)
constexpr int NT_P1   = (N_EDGES + T_TILE - 1) / T_TILE;  // 241
constexpr int ROWS_PB = 8;                       // lin1 rows per 512-thread block
constexpr int NB_LIN  = (N_NODES + ROWS_PB - 1) / ROWS_PB;  // 12500

__global__ __launch_bounds__(256) void k_zero(int* __restrict__ bcur) {
    int i = blockIdx.x * blockDim.x + threadIdx.x;
    if (i < KC) bcur[i] = i * CAP;
}

// Fused: part1 bucket sort (blocks < NT_P1) + lin1 raw GEMV (remaining blocks).
__global__ __launch_bounds__(512) void k_fused(const int* __restrict__ src,
                                               const int* __restrict__ dst,
                                               int* __restrict__ bcur,
                                               int* __restrict__ ebuf1,
                                               const float* __restrict__ x,
                                               const float* __restrict__ W1,
                                               float* __restrict__ h) {
    __shared__ int sorted[T_TILE];   // 52 KB: bucket-sorted packed edges of this tile
    __shared__ int tstart[KC];       // tile-local exclusive bucket starts
    __shared__ int cur[KC];          // pass A: histogram; pass B: ranking cursor
    __shared__ int gbase[KC];        // reserved global base per bucket

    if (blockIdx.x < NT_P1) {
        // ---------------- part1: tile-wise bucket sort ----------------
        int tid = threadIdx.x;
        int e0 = blockIdx.x * T_TILE;
        int tcnt = min(T_TILE, N_EDGES - e0);

        for (int i = tid; i < KC; i += 512) cur[i] = 0;
        __syncthreads();

        // pass A: histogram dst buckets
        for (int j = tid; j < tcnt; j += 512) {
            int d = dst[e0 + j];
            if ((unsigned)d < (unsigned)N_NODES) atomicAdd(&cur[d >> BK_SH], 1);
        }
        __syncthreads();

        // scan cur -> tstart (782 entries, 2 per thread; temp in sorted[0..511])
        {
            int i0 = 2 * tid, i1 = 2 * tid + 1;
            int a0 = (i0 < KC) ? cur[i0] : 0;
            int a1 = (i1 < KC) ? cur[i1] : 0;
            int s = a0 + a1;
            sorted[tid] = s;
            __syncthreads();
            for (int off = 1; off < 512; off <<= 1) {
                int t = (tid >= off) ? sorted[tid - off] : 0;
                __syncthreads();
                sorted[tid] += t;
                __syncthreads();
            }
            int excl = sorted[tid] - s;
            if (i0 < KC) tstart[i0] = excl;
            if (i1 < KC) tstart[i1] = excl + a0;
            __syncthreads();
        }

        // reserve global space per bucket; convert cur -> ranking cursor
        for (int i = tid; i < KC; i += 512) {
            int c = cur[i];
            gbase[i] = c ? atomicAdd(&bcur[i], c) : 0;
            cur[i] = tstart[i];
        }
        __syncthreads();

        // pass B: rank + scatter into LDS (packed (s<<7)|(d&127); s < 2^17)
        for (int j = tid; j < tcnt; j += 512) {
            int s = src[e0 + j], d = dst[e0 + j];
            if ((unsigned)s < (unsigned)N_NODES && (unsigned)d < (unsigned)N_NODES) {
                int b = d >> BK_SH;
                int r = atomicAdd(&cur[b], 1);
                sorted[r] = (s << BK_SH) | (d & (BK_N - 1));
            }
        }
        __syncthreads();

        // writeout: wave-per-bucket, contiguous LDS run -> contiguous global segment
        int wv = tid >> 6, ln = tid & 63;
        for (int b = wv; b < KC; b += 8) {
            int st = tstart[b];
            int c  = cur[b] - st;               // bucket count in this tile
            int gb = gbase[b];
            int avail = (b + 1) * CAP - gb;     // capacity guard (unreachable statistically)
            if (avail < c) c = max(avail, 0);
            for (int j = ln; j < c; j += 64)
                ebuf1[gb + j] = sorted[st + j];
        }
    } else {
        // ---------------- lin1: hls_raw[row] = x[row,:] @ W1 (no dinv yet) -------
        int wave = threadIdx.x >> 6, lane = threadIdx.x & 63;
        int row = (blockIdx.x - NT_P1) * ROWS_PB + wave;
        if (row >= N_NODES) return;
        const float4* x4 = (const float4*)(x + (size_t)row * IN_CH);
        const float4* w4 = (const float4*)W1;
        float4 acc = make_float4(0.f, 0.f, 0.f, 0.f);
#pragma unroll
        for (int j = 0; j < 2; ++j) {
            int idx = lane + 64 * j;
            float4 v = x4[idx];
            int kb = 4 * idx;
            float4 wa = w4[kb + 0], wb = w4[kb + 1], wc = w4[kb + 2], wd = w4[kb + 3];
            acc.x += v.x * wa.x + v.y * wb.x + v.z * wc.x + v.w * wd.x;
            acc.y += v.x * wa.y + v.y * wb.y + v.z * wc.y + v.w * wd.y;
            acc.z += v.x * wa.z + v.y * wb.z + v.z * wc.z + v.w * wd.z;
            acc.w += v.x * wa.w + v.y * wb.w + v.z * wc.w + v.w * wd.w;
        }
#pragma unroll
        for (int off = 32; off > 0; off >>= 1) {
            acc.x += __shfl_down(acc.x, off);
            acc.y += __shfl_down(acc.y, off);
            acc.z += __shfl_down(acc.z, off);
            acc.w += __shfl_down(acc.w, off);
        }
        if (lane == 0)
            ((float4*)h)[row] = acc;
    }
}

// Per-bucket node histogram -> CSR (nstart/ncnt); rescale hls by dinv in place.
__global__ __launch_bounds__(512) void k_csr(const int* __restrict__ bcur,
                                             const int* __restrict__ ebuf1,
                                             int* __restrict__ nstart,
                                             int* __restrict__ ncnt,
                                             float* __restrict__ hls) {
    __shared__ int hist[BK_N], excl[BK_N];
    int b = blockIdx.x, tid = threadIdx.x;
    int base = b * CAP;
    int cnt = min(bcur[b] - base, CAP);

    if (tid < BK_N) hist[tid] = 0;
    __syncthreads();
    for (int j = tid; j < cnt; j += 512)
        atomicAdd(&hist[ebuf1[base + j] & (BK_N - 1)], 1);
    __syncthreads();
    if (tid < BK_N) excl[tid] = hist[tid];
    __syncthreads();
    for (int off = 1; off < BK_N; off <<= 1) {
        int t = (tid < BK_N && tid >= off) ? excl[tid - off] : 0;
        __syncthreads();
        if (tid < BK_N) excl[tid] += t;
        __syncthreads();
    }
    if (tid < BK_N) {
        int node = b * BK_N + tid;
        if (node < N_NODES) {
            int v = hist[tid];
            nstart[node] = base + (excl[tid] - v);
            ncnt[node]   = v;
            float di = rsqrtf((float)(v + 1));   // +1 self loop
            float4* h4 = (float4*)hls;           // deferred lin1 scaling
            float4 hv = h4[node];
            h4[node] = make_float4(hv.x * di, hv.y * di, hv.z * di, hv.w * di);
        }
    }
}

// Fused part2 + layer-1 aggregation: stage bucket edges, rank-sort in LDS
// (cursors from global CSR), write ebuf2 for agg2, then gather in LDS.
__global__ __launch_bounds__(512) void k_p2agg1(const int* __restrict__ bcur,
                                                const int* __restrict__ ebuf1,
                                                const int* __restrict__ nstart,
                                                const int* __restrict__ ncnt,
                                                int* __restrict__ ebuf2,
                                                const float* __restrict__ hls,
                                                const float* __restrict__ b1,
                                                const float* __restrict__ Wmu,
                                                const float* __restrict__ Wls,
                                                float* __restrict__ ts) {
    __shared__ int stag[CAP];        // 18 KB: staged packed edges (one global read)
    __shared__ int sorted[CAP];      // 18 KB: node-sorted src indices
    __shared__ int excl_l[BK_N], cnt_l[BK_N], curx[BK_N];
    int b = blockIdx.x, tid = threadIdx.x;
    int base = b * CAP;
    int cnt = min(bcur[b] - base, CAP);

    // preload CSR for this bucket; init ranking cursors
    if (tid < BK_N) {
        int node = b * BK_N + tid;
        int st = (node < N_NODES) ? (nstart[node] - base) : 0;
        int c  = (node < N_NODES) ? ncnt[node] : 0;
        excl_l[tid] = st;
        cnt_l[tid]  = c;
        curx[tid]   = st;
    }
    // stage edges
    for (int j = tid; j < cnt; j += 512) stag[j] = ebuf1[base + j];
    __syncthreads();

    // rank + scatter into LDS (store src only; dst implied by position)
    for (int j = tid; j < cnt; j += 512) {
        int e = stag[j];
        int r = atomicAdd(&curx[e & (BK_N - 1)], 1);
        sorted[r] = e >> BK_SH;
    }
    __syncthreads();

    // writeout sorted edges for agg2 (coalesced)
    for (int j = tid; j < cnt; j += 512)
        ebuf2[base + j] = sorted[j];

    // ---- layer-1 gather: 4 threads per node, srcs from LDS, hls pre-scaled ----
    int ln = tid >> 2, r = tid & 3;              // 128 nodes x 4 threads
    int node = b * BK_N + ln;
    if (node >= N_NODES) return;                 // quad-uniform exit
    int st = excl_l[ln], c = cnt_l[ln];
    const float4* g4 = (const float4*)hls;
    float4 a0 = make_float4(0.f, 0.f, 0.f, 0.f);
    float4 a1 = make_float4(0.f, 0.f, 0.f, 0.f);
    int j = st + r, last = st + c;
    for (; j + 4 < last; j += 8) {
        int s0 = sorted[j];
        int s1 = sorted[j + 4];
        float4 f0 = g4[s0];
        float4 f1 = g4[s1];
        a0.x += f0.x; a0.y += f0.y; a0.z += f0.z; a0.w += f0.w;
        a1.x += f1.x; a1.y += f1.y; a1.z += f1.z; a1.w += f1.w;
    }
    if (j < last) {
        float4 f = g4[sorted[j]];
        a0.x += f.x; a0.y += f.y; a0.z += f.z; a0.w += f.w;
    }
    a0.x += a1.x; a0.y += a1.y; a0.z += a1.z; a0.w += a1.w;
    a0.x += __shfl_xor(a0.x, 1); a0.y += __shfl_xor(a0.y, 1);
    a0.z += __shfl_xor(a0.z, 1); a0.w += __shfl_xor(a0.w, 1);
    a0.x += __shfl_xor(a0.x, 2); a0.y += __shfl_xor(a0.y, 2);
    a0.z += __shfl_xor(a0.z, 2); a0.w += __shfl_xor(a0.w, 2);
    if (r == 0) {
        float di = rsqrtf((float)(c + 1));
        float4 self = g4[node];
        float h0 = fmaxf((a0.x + self.x) * di + b1[0], 0.f);
        float h1 = fmaxf((a0.y + self.y) * di + b1[1], 0.f);
        float h2 = fmaxf((a0.z + self.z) * di + b1[2], 0.f);
        float h3 = fmaxf((a0.w + self.w) * di + b1[3], 0.f);
        float4 o;
        o.x = (h0 * Wmu[0] + h1 * Wmu[2] + h2 * Wmu[4] + h3 * Wmu[6]) * di;
        o.y = (h0 * Wmu[1] + h1 * Wmu[3] + h2 * Wmu[5] + h3 * Wmu[7]) * di;
        o.z = (h0 * Wls[0] + h1 * Wls[2] + h2 * Wls[4] + h3 * Wls[6]) * di;
        o.w = (h0 * Wls[1] + h1 * Wls[3] + h2 * Wls[5] + h3 * Wls[7]) * di;
        ((float4*)ts)[node] = o;
    }
}

// Gather-accumulate for one node: 8 threads/node, 2x unrolled, dual accumulators.
__device__ __forceinline__ float4 gather8(const int* __restrict__ ebuf2,
                                          const float4* __restrict__ g4,
                                          int st, int c, int r) {
    float4 a0 = make_float4(0.f, 0.f, 0.f, 0.f);
    float4 a1 = make_float4(0.f, 0.f, 0.f, 0.f);
    int j = st + r, last = st + c;
    for (; j + 8 < last; j += 16) {
        int i0 = ebuf2[j];
        int i1 = ebuf2[j + 8];
        float4 f0 = g4[i0];
        float4 f1 = g4[i1];
        a0.x += f0.x; a0.y += f0.y; a0.z += f0.z; a0.w += f0.w;
        a1.x += f1.x; a1.y += f1.y; a1.z += f1.z; a1.w += f1.w;
    }
    if (j < last) {
        float4 f = g4[ebuf2[j]];
        a0.x += f.x; a0.y += f.y; a0.z += f.z; a0.w += f.w;
    }
    a0.x += a1.x; a0.y += a1.y; a0.z += a1.z; a0.w += a1.w;
    a0.x += __shfl_xor(a0.x, 1); a0.y += __shfl_xor(a0.y, 1);
    a0.z += __shfl_xor(a0.z, 1); a0.w += __shfl_xor(a0.w, 1);
    a0.x += __shfl_xor(a0.x, 2); a0.y += __shfl_xor(a0.y, 2);
    a0.z += __shfl_xor(a0.z, 2); a0.w += __shfl_xor(a0.w, 2);
    a0.x += __shfl_xor(a0.x, 4); a0.y += __shfl_xor(a0.y, 4);
    a0.z += __shfl_xor(a0.z, 4); a0.w += __shfl_xor(a0.w, 4);
    return a0;
}

// Layer-2 aggregation on ts -> mu (out[0..2N)), logstd (out[2N..4N)).
__global__ __launch_bounds__(256) void k_agg2(const int* __restrict__ ebuf2,
                                              const int* __restrict__ nstart,
                                              const int* __restrict__ ncnt,
                                              const float* __restrict__ ts,
                                              const float* __restrict__ bmu,
                                              const float* __restrict__ bls,
                                              float* __restrict__ out) {
    int tid = threadIdx.x;
    int node = blockIdx.x * 32 + (tid >> 3);
    int r = tid & 7;
    if (node >= N_NODES) return;
    const float4* g4 = (const float4*)ts;
    int c = ncnt[node];
    float4 a = gather8(ebuf2, g4, nstart[node], c, r);
    if (r == 0) {
        float4 self = g4[node];
        float di = rsqrtf((float)(c + 1));
        float2 mu = make_float2((a.x + self.x) * di + bmu[0],
                                (a.y + self.y) * di + bmu[1]);
        float2 ls = make_float2((a.z + self.z) * di + bls[0],
                                (a.w + self.w) * di + bls[1]);
        ((float2*)out)[node] = mu;
        ((float2*)(out + 2 * N_NODES))[node] = ls;
    }
}

extern "C" void kernel_launch(void* const* d_in, const int* in_sizes, int n_in,
                              void* d_out, int out_size, void* d_ws, size_t ws_size,
                              hipStream_t stream) {
    const float* x    = (const float*)d_in[0];
    const int*   ei   = (const int*)d_in[1];    // [2, E] int32: src row then dst row
    const float* W1   = (const float*)d_in[2];
    const float* b1   = (const float*)d_in[3];
    const float* Wmu  = (const float*)d_in[4];
    const float* bmu  = (const float*)d_in[5];
    const float* Wls  = (const float*)d_in[6];
    const float* bls  = (const float*)d_in[7];
    float* out = (float*)d_out;

    const int* src = ei;
    const int* dst = ei + N_EDGES;

    // workspace layout (~33 MB)
    char* p = (char*)d_ws;
    float* hls    = (float*)p;  p += (size_t)N_NODES * 16;
    float* ts     = (float*)p;  p += (size_t)N_NODES * 16;
    int*   nstart = (int*)p;    p += (size_t)N_NODES * 4;
    int*   ncnt   = (int*)p;    p += (size_t)N_NODES * 4;
    int*   bcur   = (int*)p;    p += (size_t)KC * 4;
    int*   ebuf1  = (int*)p;    p += (size_t)KC * CAP * 4;   // 14.4 MB
    int*   ebuf2  = (int*)p;    p += (size_t)KC * CAP * 4;   // 14.4 MB

    const int TB = 256;
    int gA = (N_NODES + 31) / 32;     // 3125

    k_zero  <<<(KC + TB - 1) / TB, TB, 0, stream>>>(bcur);
    k_fused <<<NT_P1 + NB_LIN, 512, 0, stream>>>(src, dst, bcur, ebuf1, x, W1, hls);
    k_csr   <<<KC, 512, 0, stream>>>(bcur, ebuf1, nstart, ncnt, hls);
    k_p2agg1<<<KC, 512, 0, stream>>>(bcur, ebuf1, nstart, ncnt, ebuf2, hls,
                                     b1, Wmu, Wls, ts);
    k_agg2  <<<gA, TB, 0, stream>>>(ebuf2, nstart, ncnt, ts, bmu, bls, out);
}

// Round 6
// 364.485 us; speedup vs baseline: 4.5515x; 1.0481x over previous
//
#include <hip/hip_runtime.h>

// VariationalGCNEncoder: 2-layer GCN (512 -> 4 -> [2,2]), N=100k nodes, E=3.2M edges.
//
// R12 = R11 with k_fused's LDS halved (T_TILE 13312 -> 7424, 61.5KB -> 39KB)
// so the fused kernel runs 4 blocks/CU (32 waves/CU) instead of 2 (16 waves).
// R11 profile: k_fused = 118.9us at 15% HBM, 16% VALU, 36% occupancy -> pure
// latency-bound at LDS-capped occupancy; the 12.5k lin1 blocks paid part1's
// LDS footprint. Smaller tiles double TLP for both halves; writeout runs
// shrink 17 -> 9.5 edges but land in L2/L3 (19MB total, bounded cost).
//
//   k_zero   : bcur[b] = b*CAP
//   k_fused  : blocks [0,432): tile->LDS 2-pass bucket sort (782 buckets of 128),
//              coalesced writeout to ebuf1 (packed (s<<7)|(d&127));
//              blocks [432,+12500): hls_raw = x @ W1 (wave-per-row, float4)
//   k_csr    : per-bucket node histogram of ebuf1 -> nstart/ncnt; hls *= dinv
//   k_p2agg1 : per-bucket: stage ebuf1 -> rank-sort in LDS -> write ebuf2;
//              then layer-1 gather IN LDS (4 thr/node) -> relu -> ts
//   k_agg2   : per-node CSR gather on ts (8 thr/node) -> mu, logstd -> d_out

constexpr int N_NODES = 100000;
constexpr int N_EDGES = 3200000;
constexpr int IN_CH   = 512;
constexpr int BK_SH   = 7;                       // 128 nodes per bucket
constexpr int BK_N    = 1 << BK_SH;              // 128
constexpr int KC      = (N_NODES + BK_N - 1) / BK_N;    // 782
constexpr int CAP     = 4608;                    // per-bucket capacity (mean 4092)
constexpr int T_TILE  = 7424;                    // edges per part1 tile (29KB LDS)
constexpr int NT_P1   = (N_EDGES + T_TILE - 1) / T_TILE;  // 432
constexpr int ROWS_PB = 8;                       // lin1 rows per 512-thread block
constexpr int NB_LIN  = (N_NODES + ROWS_PB - 1) / ROWS_PB;  // 12500

__global__ __launch_bounds__(256) void k_zero(int* __restrict__ bcur) {
    int i = blockIdx.x * blockDim.x + threadIdx.x;
    if (i < KC) bcur[i] = i * CAP;
}

// Fused: part1 bucket sort (blocks < NT_P1) + lin1 raw GEMV (remaining blocks).
__global__ __launch_bounds__(512) void k_fused(const int* __restrict__ src,
                                               const int* __restrict__ dst,
                                               int* __restrict__ bcur,
                                               int* __restrict__ ebuf1,
                                               const float* __restrict__ x,
                                               const float* __restrict__ W1,
                                               float* __restrict__ h) {
    __shared__ int sorted[T_TILE];   // 29 KB: bucket-sorted packed edges of this tile
    __shared__ int tstart[KC];       // tile-local exclusive bucket starts
    __shared__ int cur[KC];          // pass A: histogram; pass B: ranking cursor
    __shared__ int gbase[KC];        // reserved global base per bucket

    if (blockIdx.x < NT_P1) {
        // ---------------- part1: tile-wise bucket sort ----------------
        int tid = threadIdx.x;
        int e0 = blockIdx.x * T_TILE;
        int tcnt = min(T_TILE, N_EDGES - e0);

        for (int i = tid; i < KC; i += 512) cur[i] = 0;
        __syncthreads();

        // pass A: histogram dst buckets
        for (int j = tid; j < tcnt; j += 512) {
            int d = dst[e0 + j];
            if ((unsigned)d < (unsigned)N_NODES) atomicAdd(&cur[d >> BK_SH], 1);
        }
        __syncthreads();

        // scan cur -> tstart (782 entries, 2 per thread; temp in sorted[0..511])
        {
            int i0 = 2 * tid, i1 = 2 * tid + 1;
            int a0 = (i0 < KC) ? cur[i0] : 0;
            int a1 = (i1 < KC) ? cur[i1] : 0;
            int s = a0 + a1;
            sorted[tid] = s;
            __syncthreads();
            for (int off = 1; off < 512; off <<= 1) {
                int t = (tid >= off) ? sorted[tid - off] : 0;
                __syncthreads();
                sorted[tid] += t;
                __syncthreads();
            }
            int excl = sorted[tid] - s;
            if (i0 < KC) tstart[i0] = excl;
            if (i1 < KC) tstart[i1] = excl + a0;
            __syncthreads();
        }

        // reserve global space per bucket; convert cur -> ranking cursor
        for (int i = tid; i < KC; i += 512) {
            int c = cur[i];
            gbase[i] = c ? atomicAdd(&bcur[i], c) : 0;
            cur[i] = tstart[i];
        }
        __syncthreads();

        // pass B: rank + scatter into LDS (packed (s<<7)|(d&127); s < 2^17)
        for (int j = tid; j < tcnt; j += 512) {
            int s = src[e0 + j], d = dst[e0 + j];
            if ((unsigned)s < (unsigned)N_NODES && (unsigned)d < (unsigned)N_NODES) {
                int b = d >> BK_SH;
                int r = atomicAdd(&cur[b], 1);
                sorted[r] = (s << BK_SH) | (d & (BK_N - 1));
            }
        }
        __syncthreads();

        // writeout: wave-per-bucket, contiguous LDS run -> contiguous global segment
        int wv = tid >> 6, ln = tid & 63;
        for (int b = wv; b < KC; b += 8) {
            int st = tstart[b];
            int c  = cur[b] - st;               // bucket count in this tile
            int gb = gbase[b];
            int avail = (b + 1) * CAP - gb;     // capacity guard (unreachable statistically)
            if (avail < c) c = max(avail, 0);
            for (int j = ln; j < c; j += 64)
                ebuf1[gb + j] = sorted[st + j];
        }
    } else {
        // ---------------- lin1: hls_raw[row] = x[row,:] @ W1 (no dinv yet) -------
        int wave = threadIdx.x >> 6, lane = threadIdx.x & 63;
        int row = (blockIdx.x - NT_P1) * ROWS_PB + wave;
        if (row >= N_NODES) return;
        const float4* x4 = (const float4*)(x + (size_t)row * IN_CH);
        const float4* w4 = (const float4*)W1;
        float4 acc = make_float4(0.f, 0.f, 0.f, 0.f);
#pragma unroll
        for (int j = 0; j < 2; ++j) {
            int idx = lane + 64 * j;
            float4 v = x4[idx];
            int kb = 4 * idx;
            float4 wa = w4[kb + 0], wb = w4[kb + 1], wc = w4[kb + 2], wd = w4[kb + 3];
            acc.x += v.x * wa.x + v.y * wb.x + v.z * wc.x + v.w * wd.x;
            acc.y += v.x * wa.y + v.y * wb.y + v.z * wc.y + v.w * wd.y;
            acc.z += v.x * wa.z + v.y * wb.z + v.z * wc.z + v.w * wd.z;
            acc.w += v.x * wa.w + v.y * wb.w + v.z * wc.w + v.w * wd.w;
        }
#pragma unroll
        for (int off = 32; off > 0; off >>= 1) {
            acc.x += __shfl_down(acc.x, off);
            acc.y += __shfl_down(acc.y, off);
            acc.z += __shfl_down(acc.z, off);
            acc.w += __shfl_down(acc.w, off);
        }
        if (lane == 0)
            ((float4*)h)[row] = acc;
    }
}

// Per-bucket node histogram -> CSR (nstart/ncnt); rescale hls by dinv in place.
__global__ __launch_bounds__(512) void k_csr(const int* __restrict__ bcur,
                                             const int* __restrict__ ebuf1,
                                             int* __restrict__ nstart,
                                             int* __restrict__ ncnt,
                                             float* __restrict__ hls) {
    __shared__ int hist[BK_N], excl[BK_N];
    int b = blockIdx.x, tid = threadIdx.x;
    int base = b * CAP;
    int cnt = min(bcur[b] - base, CAP);

    if (tid < BK_N) hist[tid] = 0;
    __syncthreads();
    for (int j = tid; j < cnt; j += 512)
        atomicAdd(&hist[ebuf1[base + j] & (BK_N - 1)], 1);
    __syncthreads();
    if (tid < BK_N) excl[tid] = hist[tid];
    __syncthreads();
    for (int off = 1; off < BK_N; off <<= 1) {
        int t = (tid < BK_N && tid >= off) ? excl[tid - off] : 0;
        __syncthreads();
        if (tid < BK_N) excl[tid] += t;
        __syncthreads();
    }
    if (tid < BK_N) {
        int node = b * BK_N + tid;
        if (node < N_NODES) {
            int v = hist[tid];
            nstart[node] = base + (excl[tid] - v);
            ncnt[node]   = v;
            float di = rsqrtf((float)(v + 1));   // +1 self loop
            float4* h4 = (float4*)hls;           // deferred lin1 scaling
            float4 hv = h4[node];
            h4[node] = make_float4(hv.x * di, hv.y * di, hv.z * di, hv.w * di);
        }
    }
}

// Fused part2 + layer-1 aggregation: stage bucket edges, rank-sort in LDS
// (cursors from global CSR), write ebuf2 for agg2, then gather in LDS.
__global__ __launch_bounds__(512) void k_p2agg1(const int* __restrict__ bcur,
                                                const int* __restrict__ ebuf1,
                                                const int* __restrict__ nstart,
                                                const int* __restrict__ ncnt,
                                                int* __restrict__ ebuf2,
                                                const float* __restrict__ hls,
                                                const float* __restrict__ b1,
                                                const float* __restrict__ Wmu,
                                                const float* __restrict__ Wls,
                                                float* __restrict__ ts) {
    __shared__ int stag[CAP];        // 18 KB: staged packed edges (one global read)
    __shared__ int sorted[CAP];      // 18 KB: node-sorted src indices
    __shared__ int excl_l[BK_N], cnt_l[BK_N], curx[BK_N];
    int b = blockIdx.x, tid = threadIdx.x;
    int base = b * CAP;
    int cnt = min(bcur[b] - base, CAP);

    // preload CSR for this bucket; init ranking cursors
    if (tid < BK_N) {
        int node = b * BK_N + tid;
        int st = (node < N_NODES) ? (nstart[node] - base) : 0;
        int c  = (node < N_NODES) ? ncnt[node] : 0;
        excl_l[tid] = st;
        cnt_l[tid]  = c;
        curx[tid]   = st;
    }
    // stage edges
    for (int j = tid; j < cnt; j += 512) stag[j] = ebuf1[base + j];
    __syncthreads();

    // rank + scatter into LDS (store src only; dst implied by position)
    for (int j = tid; j < cnt; j += 512) {
        int e = stag[j];
        int r = atomicAdd(&curx[e & (BK_N - 1)], 1);
        sorted[r] = e >> BK_SH;
    }
    __syncthreads();

    // writeout sorted edges for agg2 (coalesced)
    for (int j = tid; j < cnt; j += 512)
        ebuf2[base + j] = sorted[j];

    // ---- layer-1 gather: 4 threads per node, srcs from LDS, hls pre-scaled ----
    int ln = tid >> 2, r = tid & 3;              // 128 nodes x 4 threads
    int node = b * BK_N + ln;
    if (node >= N_NODES) return;                 // quad-uniform exit
    int st = excl_l[ln], c = cnt_l[ln];
    const float4* g4 = (const float4*)hls;
    float4 a0 = make_float4(0.f, 0.f, 0.f, 0.f);
    float4 a1 = make_float4(0.f, 0.f, 0.f, 0.f);
    int j = st + r, last = st + c;
    for (; j + 4 < last; j += 8) {
        int s0 = sorted[j];
        int s1 = sorted[j + 4];
        float4 f0 = g4[s0];
        float4 f1 = g4[s1];
        a0.x += f0.x; a0.y += f0.y; a0.z += f0.z; a0.w += f0.w;
        a1.x += f1.x; a1.y += f1.y; a1.z += f1.z; a1.w += f1.w;
    }
    if (j < last) {
        float4 f = g4[sorted[j]];
        a0.x += f.x; a0.y += f.y; a0.z += f.z; a0.w += f.w;
    }
    a0.x += a1.x; a0.y += a1.y; a0.z += a1.z; a0.w += a1.w;
    a0.x += __shfl_xor(a0.x, 1); a0.y += __shfl_xor(a0.y, 1);
    a0.z += __shfl_xor(a0.z, 1); a0.w += __shfl_xor(a0.w, 1);
    a0.x += __shfl_xor(a0.x, 2); a0.y += __shfl_xor(a0.y, 2);
    a0.z += __shfl_xor(a0.z, 2); a0.w += __shfl_xor(a0.w, 2);
    if (r == 0) {
        float di = rsqrtf((float)(c + 1));
        float4 self = g4[node];
        float h0 = fmaxf((a0.x + self.x) * di + b1[0], 0.f);
        float h1 = fmaxf((a0.y + self.y) * di + b1[1], 0.f);
        float h2 = fmaxf((a0.z + self.z) * di + b1[2], 0.f);
        float h3 = fmaxf((a0.w + self.w) * di + b1[3], 0.f);
        float4 o;
        o.x = (h0 * Wmu[0] + h1 * Wmu[2] + h2 * Wmu[4] + h3 * Wmu[6]) * di;
        o.y = (h0 * Wmu[1] + h1 * Wmu[3] + h2 * Wmu[5] + h3 * Wmu[7]) * di;
        o.z = (h0 * Wls[0] + h1 * Wls[2] + h2 * Wls[4] + h3 * Wls[6]) * di;
        o.w = (h0 * Wls[1] + h1 * Wls[3] + h2 * Wls[5] + h3 * Wls[7]) * di;
        ((float4*)ts)[node] = o;
    }
}

// Gather-accumulate for one node: 8 threads/node, 2x unrolled, dual accumulators.
__device__ __forceinline__ float4 gather8(const int* __restrict__ ebuf2,
                                          const float4* __restrict__ g4,
                                          int st, int c, int r) {
    float4 a0 = make_float4(0.f, 0.f, 0.f, 0.f);
    float4 a1 = make_float4(0.f, 0.f, 0.f, 0.f);
    int j = st + r, last = st + c;
    for (; j + 8 < last; j += 16) {
        int i0 = ebuf2[j];
        int i1 = ebuf2[j + 8];
        float4 f0 = g4[i0];
        float4 f1 = g4[i1];
        a0.x += f0.x; a0.y += f0.y; a0.z += f0.z; a0.w += f0.w;
        a1.x += f1.x; a1.y += f1.y; a1.z += f1.z; a1.w += f1.w;
    }
    if (j < last) {
        float4 f = g4[ebuf2[j]];
        a0.x += f.x; a0.y += f.y; a0.z += f.z; a0.w += f.w;
    }
    a0.x += a1.x; a0.y += a1.y; a0.z += a1.z; a0.w += a1.w;
    a0.x += __shfl_xor(a0.x, 1); a0.y += __shfl_xor(a0.y, 1);
    a0.z += __shfl_xor(a0.z, 1); a0.w += __shfl_xor(a0.w, 1);
    a0.x += __shfl_xor(a0.x, 2); a0.y += __shfl_xor(a0.y, 2);
    a0.z += __shfl_xor(a0.z, 2); a0.w += __shfl_xor(a0.w, 2);
    a0.x += __shfl_xor(a0.x, 4); a0.y += __shfl_xor(a0.y, 4);
    a0.z += __shfl_xor(a0.z, 4); a0.w += __shfl_xor(a0.w, 4);
    return a0;
}

// Layer-2 aggregation on ts -> mu (out[0..2N)), logstd (out[2N..4N)).
__global__ __launch_bounds__(256) void k_agg2(const int* __restrict__ ebuf2,
                                              const int* __restrict__ nstart,
                                              const int* __restrict__ ncnt,
                                              const float* __restrict__ ts,
                                              const float* __restrict__ bmu,
                                              const float* __restrict__ bls,
                                              float* __restrict__ out) {
    int tid = threadIdx.x;
    int node = blockIdx.x * 32 + (tid >> 3);
    int r = tid & 7;
    if (node >= N_NODES) return;
    const float4* g4 = (const float4*)ts;
    int c = ncnt[node];
    float4 a = gather8(ebuf2, g4, nstart[node], c, r);
    if (r == 0) {
        float4 self = g4[node];
        float di = rsqrtf((float)(c + 1));
        float2 mu = make_float2((a.x + self.x) * di + bmu[0],
                                (a.y + self.y) * di + bmu[1]);
        float2 ls = make_float2((a.z + self.z) * di + bls[0],
                                (a.w + self.w) * di + bls[1]);
        ((float2*)out)[node] = mu;
        ((float2*)(out + 2 * N_NODES))[node] = ls;
    }
}

extern "C" void kernel_launch(void* const* d_in, const int* in_sizes, int n_in,
                              void* d_out, int out_size, void* d_ws, size_t ws_size,
                              hipStream_t stream) {
    const float* x    = (const float*)d_in[0];
    const int*   ei   = (const int*)d_in[1];    // [2, E] int32: src row then dst row
    const float* W1   = (const float*)d_in[2];
    const float* b1   = (const float*)d_in[3];
    const float* Wmu  = (const float*)d_in[4];
    const float* bmu  = (const float*)d_in[5];
    const float* Wls  = (const float*)d_in[6];
    const float* bls  = (const float*)d_in[7];
    float* out = (float*)d_out;

    const int* src = ei;
    const int* dst = ei + N_EDGES;

    // workspace layout (~33 MB)
    char* p = (char*)d_ws;
    float* hls    = (float*)p;  p += (size_t)N_NODES * 16;
    float* ts     = (float*)p;  p += (size_t)N_NODES * 16;
    int*   nstart = (int*)p;    p += (size_t)N_NODES * 4;
    int*   ncnt   = (int*)p;    p += (size_t)N_NODES * 4;
    int*   bcur   = (int*)p;    p += (size_t)KC * 4;
    int*   ebuf1  = (int*)p;    p += (size_t)KC * CAP * 4;   // 14.4 MB
    int*   ebuf2  = (int*)p;    p += (size_t)KC * CAP * 4;   // 14.4 MB

    const int TB = 256;
    int gA = (N_NODES + 31) / 32;     // 3125

    k_zero  <<<(KC + TB - 1) / TB, TB, 0, stream>>>(bcur);
    k_fused <<<NT_P1 + NB_LIN, 512, 0, stream>>>(src, dst, bcur, ebuf1, x, W1, hls);
    k_csr   <<<KC, 512, 0, stream>>>(bcur, ebuf1, nstart, ncnt, hls);
    k_p2agg1<<<KC, 512, 0, stream>>>(bcur, ebuf1, nstart, ncnt, ebuf2, hls,
                                     b1, Wmu, Wls, ts);
    k_agg2  <<<gA, TB, 0, stream>>>(ebuf2, nstart, ncnt, ts, bmu, bls, out);
}